// Round 20
// baseline (256.659 us; speedup 1.0000x reference)
//
#include <hip/hip_runtime.h>

// Problem constants
#define D_    2048
#define OUT_  2048
#define E_    8
#define R_    16
#define KX    2176          // D_ + E_*R_  (K-extended GEMM depth)
#define M_    16384         // B*S tokens
#define SCALING_F 2.0f      // ALPHA / R = 32/16

typedef unsigned short ushort_t;
typedef unsigned short ushort8 __attribute__((ext_vector_type(8)));
typedef __bf16 bf16x8 __attribute__((ext_vector_type(8)));
typedef float f32x4 __attribute__((ext_vector_type(4)));

__device__ __forceinline__ ushort_t f2bf(float f) {
  unsigned u = __float_as_uint(f);
  u += 0x7FFFu + ((u >> 16) & 1u);   // round-to-nearest-even
  return (ushort_t)(u >> 16);
}

#define GLOAD16(gp, lp)                                                        \
  __builtin_amdgcn_global_load_lds(                                            \
      (const __attribute__((address_space(1))) void*)(gp),                     \
      (__attribute__((address_space(3))) void*)(lp), 16, 0, 0)

// -------- W_ext + A_ext prep (fused): wext[OUT_][KX], aext[128][D_] bf16 ----
__global__ __launch_bounds__(256) void wprep_all_kernel(
    const float* __restrict__ W, const float* __restrict__ Bw,
    const float* __restrict__ A,
    ushort_t* __restrict__ wext, ushort_t* __restrict__ aext)
{
  const int bid = blockIdx.x;
  const int t = threadIdx.x;
  if (bid < OUT_) {
    const int o = bid;
    const float* wr = W + (size_t)o * D_ + t * 8;
    float4 v0 = *(const float4*)wr;
    float4 v1 = *(const float4*)(wr + 4);
    ushort8 wb;
    wb[0] = f2bf(v0.x); wb[1] = f2bf(v0.y); wb[2] = f2bf(v0.z); wb[3] = f2bf(v0.w);
    wb[4] = f2bf(v1.x); wb[5] = f2bf(v1.y); wb[6] = f2bf(v1.z); wb[7] = f2bf(v1.w);
    *(ushort8*)(wext + (size_t)o * KX + t * 8) = wb;
    if (t < E_ * R_) {
      const int e = t >> 4, r = t & 15;
      wext[(size_t)o * KX + D_ + t] = f2bf(Bw[((size_t)e * OUT_ + o) * R_ + r]);
    }
  } else {
    const size_t i = ((size_t)(bid - OUT_) * 256 + t) * 8;
    float4 v0 = *(const float4*)(A + i);
    float4 v1 = *(const float4*)(A + i + 4);
    ushort8 b;
    b[0] = f2bf(v0.x); b[1] = f2bf(v0.y); b[2] = f2bf(v0.z); b[3] = f2bf(v0.w);
    b[4] = f2bf(v1.x); b[5] = f2bf(v1.y); b[6] = f2bf(v1.z); b[7] = f2bf(v1.w);
    *(ushort8*)(aext + i) = b;
  }
}

// ---- FUSED h GEMM + router + x convert (r10/r16/r19 best-measured) ---------
#define HG_NKT (D_ / 64)     // 32 K-tiles

__global__ __launch_bounds__(256) void hrouter_kernel(
    const float* __restrict__ x,       // [M_][D_] fp32
    const float* __restrict__ rW,      // [E_][D_] fp32
    const ushort_t* __restrict__ Ae,   // [128][D_] bf16
    ushort_t* __restrict__ xext)       // writes all KX cols
{
  __shared__ __attribute__((aligned(16))) char lds[40960];  // 2 x (4KB X + 16KB A)
  __shared__ int esel[32];

  const int t = threadIdx.x;
  const int lane = t & 63, w = t >> 6;
  const int wr = w >> 1, wc = w & 1;          // wave tile 16 rows x 64 cols
  const int lr = lane & 15, lg = lane >> 4;
  const int koff = (lr & 7) << 4;

  const int bm = blockIdx.x;                   // 512 blocks x 32 rows
  const size_t row0 = (size_t)bm * 32;

  const int sg_row = t >> 3;                   // 0..31
  const int sg_c = t & 7;                      // col chunk (8 bf16)
  const int sg_slotx = sg_c ^ (sg_row & 7);    // pre-swizzled slot

  auto stageA = [&](int TT) {
    char* dst = lds + (TT & 1) * 20480 + 4096;
    #pragma unroll
    for (int g = 0; g < 4; ++g) {
      const int r = g * 32 + sg_row;
      GLOAD16(Ae + (size_t)r * D_ + TT * 64 + sg_slotx * 8,
              dst + g * 4096 + t * 16);
    }
  };
  auto putX = [&](int TT, const float4& a, const float4& b) {
    ushort8 xb;
    xb[0] = f2bf(a.x); xb[1] = f2bf(a.y); xb[2] = f2bf(a.z); xb[3] = f2bf(a.w);
    xb[4] = f2bf(b.x); xb[5] = f2bf(b.y); xb[6] = f2bf(b.z); xb[7] = f2bf(b.w);
    char* Xb = lds + (TT & 1) * 20480;
    *(ushort8*)(Xb + sg_row * 128 + sg_slotx * 16) = xb;
    *(ushort8*)(xext + (row0 + sg_row) * KX + TT * 64 + sg_c * 8) = xb;
  };

  float la[E_];
  #pragma unroll
  for (int e = 0; e < E_; ++e) la[e] = 0.f;
  // accumulate this thread's 8-element slice of the row's router logits
  auto accLogit = [&](int TT, const float4& a, const float4& b) {
    const float* wp = rW + TT * 64 + sg_c * 8;
    #pragma unroll
    for (int e = 0; e < E_; ++e) {
      float4 w0 = *(const float4*)(wp + (size_t)e * D_);
      float4 w1 = *(const float4*)(wp + (size_t)e * D_ + 4);
      la[e] += a.x * w0.x + a.y * w0.y + a.z * w0.z + a.w * w0.w
             + b.x * w1.x + b.y * w1.y + b.z * w1.z + b.w * w1.w;
    }
  };

  f32x4 acc[4] = {};

  {
    const float* xp = x + (row0 + sg_row) * D_ + sg_c * 8;
    float4 a = *(const float4*)xp;
    float4 b = *(const float4*)(xp + 4);
    stageA(0);
    putX(0, a, b);
    accLogit(0, a, b);
  }
  __syncthreads();

  for (int T = 0; T < HG_NKT; ++T) {
    float4 na, nb;
    const bool more = (T + 1 < HG_NKT);
    if (more) {
      const float* xp = x + (row0 + sg_row) * D_ + (T + 1) * 64 + sg_c * 8;
      na = *(const float4*)xp;
      nb = *(const float4*)(xp + 4);
      stageA(T + 1);
    }
    char* Xb = lds + (T & 1) * 20480;
    char* Ab = Xb + 4096;
    bf16x8 af[2], bfr[4][2];
    #pragma unroll
    for (int kk = 0; kk < 2; ++kk)
      af[kk] = *(const bf16x8*)(Xb + (wr * 16 + lr) * 128 + ((kk * 64 + lg * 16) ^ koff));
    #pragma unroll
    for (int nj = 0; nj < 4; ++nj) {
      const int R = wc * 64 + nj * 16 + lr;
      #pragma unroll
      for (int kk = 0; kk < 2; ++kk)
        bfr[nj][kk] = *(const bf16x8*)(Ab + R * 128 + ((kk * 64 + lg * 16) ^ koff));
    }
    #pragma unroll
    for (int nj = 0; nj < 4; ++nj)
      #pragma unroll
      for (int kk = 0; kk < 2; ++kk)
        acc[nj] = __builtin_amdgcn_mfma_f32_16x16x32_bf16(af[kk], bfr[nj][kk], acc[nj], 0, 0, 0);
    if (more) {
      putX(T + 1, na, nb);
      accLogit(T + 1, na, nb);
    }
    __syncthreads();   // full drain: vmcnt (Ae tile) + lgkm (Xb writes)
  }

  // router finish: 8-lane group (one x-row) fp64 tree reduce + first-max argmax
  {
    double s[E_];
    #pragma unroll
    for (int e = 0; e < E_; ++e) s[e] = (double)la[e];
    #pragma unroll
    for (int off = 1; off <= 4; off <<= 1)
      #pragma unroll
      for (int e = 0; e < E_; ++e) s[e] += __shfl_xor(s[e], off, 64);
    int bi = 0; double best = s[0];
    #pragma unroll
    for (int e = 1; e < E_; ++e)
      if (s[e] > best) { best = s[e]; bi = e; }   // first-max tie-break
    if (sg_c == 0) esel[sg_row] = bi;
  }
  __syncthreads();

  // masked epilogue: xext[row][D_+col] = (esel[row]==col>>4) ? bf16(2*h) : 0
  int er[4];
  #pragma unroll
  for (int rr = 0; rr < 4; ++rr)
    er[rr] = esel[wr * 16 + lg * 4 + rr];
  #pragma unroll
  for (int nj = 0; nj < 4; ++nj) {
    const int col = wc * 64 + nj * 16 + lr;
    const int ecol = wc * 4 + nj;              // col>>4, wave-uniform per nj
    #pragma unroll
    for (int rr = 0; rr < 4; ++rr) {
      const size_t row = row0 + wr * 16 + lg * 4 + rr;
      ushort_t v = (er[rr] == ecol) ? f2bf(acc[nj][rr] * SCALING_F) : (ushort_t)0;
      xext[row * KX + D_ + col] = v;
    }
  }
}

// --- GEMM: 256x256, 8-phase, 1 barrier/phase + aq REGISTER PREFETCH ---------
// r17 schedule (136 barriers, proven optimum of the density scan) + one
// change: per phase p with q<3, AFTER barrier(p) issue the NEXT phase's 4
// aq ds_reads into the alternate register buffer, then wait lgkmcnt(4)
// (FIFO DS returns: drains this phase's reads, keeps the prefetch in
// flight under the 16-MFMA cluster). q==3 phases keep lgkmcnt(0) (p3->p4 /
// p7->p0 cross buffers; safety needs the vmcnt+barrier handoff).
// lgkm ledger: p0/p4 wait with 16 outstanding (12 pre-barrier bq+aq + 4
// prefetch) -> drains 12; p1/p2/p5/p6 with 8 -> drains 4; p3/p7 drain all.
// Prefetch hazards (skew <= 1 barrier window): prefetch@p reads
// buf(tile).A rows of phase p+1. Stages in windows p and p+1:
//   p0:B1->buf1.B  p1:A->buf1.A  p2:B0->buf0.B   (prefetch reads buf0.A)
//   p4:B1->buf0.B  p5:A->buf0.A  p6:B0->buf1.B   (prefetch reads buf1.A)
// all disjoint from the prefetched region. Stage-vs-reads(p-1..p) rules
// unchanged from r17. MFMA operand order bit-identical -> same absmax.
#define NKT (KX / 64)        // 34 K-tiles
#define NITER (NKT / 2)      // 17 iterations
#define NSTG (NKT * 4)       // 136 half-tile stages

__global__ __launch_bounds__(512, 2) void gemm_kernel(
    const ushort_t* __restrict__ Ag,   // [M_][KX] bf16
    const ushort_t* __restrict__ Bg,   // [OUT_][KX] bf16
    const float* __restrict__ bias,
    float* __restrict__ C)
{
  __shared__ __attribute__((aligned(16))) char lds[131072];

  const int t = threadIdx.x;
  const int lane = t & 63, w = t >> 6;
  const int wm = w >> 2, wn = w & 3;          // 2x4 wave grid; wave tile 128x64
  const int lr = lane & 15, lg = lane >> 4;
  const int koff = (lr & 7) << 4;             // read-side swizzle XOR (bytes)

  // XCD-bijective blockIdx swizzle (512 % 8 == 0)
  const int swz = (blockIdx.x & 7) * 64 + (blockIdx.x >> 3);
  const int bm = swz >> 3, bn = swz & 7;

  const int sg_row = t >> 3;
  const int sg_slotx = (t & 7) ^ ((t >> 3) & 7);   // pre-swizzled source slot
  const size_t aRow0 = (size_t)bm * 256;
  const size_t bRow0 = (size_t)bn * 256;

  // stage half-tile s: tile TT=s>>2, j=s&3 (0,1 = A halves; 2,3 = B halves)
  auto stage = [&](int s) {
    if (s >= NSTG) return;
    const int TT = s >> 2, j = s & 3;
    const int isB = j >> 1, half = j & 1;
    const ushort_t* src = isB ? Bg : Ag;
    const size_t gr0 = (isB ? bRow0 : aRow0) + half * 128;
    char* dst = lds + (TT & 1) * 65536 + isB * 32768 + half * 16384;
    #pragma unroll
    for (int g = 0; g < 2; ++g) {
      const int r = g * 64 + sg_row;
      GLOAD16(src + (gr0 + r) * KX + TT * 64 + sg_slotx * 8,
              dst + g * 8192 + t * 16);
    }
  };

  f32x4 acc[8][4] = {};
  bf16x8 bq[4][2];
  bf16x8 aqbuf[2][2][2];   // [parity][i][kk] — cur = aqbuf[p&1]

  // prologue: tile0 {A0,A1,B0,B1} + B0(1); wait tile0 landed, B0(1) in flight.
  stage(0); stage(1); stage(2); stage(3);
  stage(6);
  asm volatile("s_waitcnt vmcnt(2)" ::: "memory");
  __builtin_amdgcn_s_barrier();

  for (int ii = 0; ii < NITER; ++ii) {
    #pragma unroll
    for (int p = 0; p < 8; ++p) {
      const int q = p & 3;
      char* Ab = lds + ((2 * ii + (p >> 2)) & 1) * 65536;
      char* Bb = Ab + 32768;
      // --- pre-barrier reads at q==0 only: bq (8) + this phase's aq (4) ---
      if (q == 0) {
        #pragma unroll
        for (int nj = 0; nj < 4; ++nj) {
          const int R = wn * 64 + nj * 16 + lr;
          #pragma unroll
          for (int kk = 0; kk < 2; ++kk)
            bq[nj][kk] = *(const bf16x8*)(Bb + R * 128 + ((kk * 64 + lg * 16) ^ koff));
        }
        #pragma unroll
        for (int i = 0; i < 2; ++i) {
          const int R = wm * 128 + i * 16 + lr;
          #pragma unroll
          for (int kk = 0; kk < 2; ++kk)
            aqbuf[p & 1][i][kk] = *(const bf16x8*)(Ab + R * 128 + ((kk * 64 + lg * 16) ^ koff));
        }
      }
      // --- 1-barrier stage map (r17 ledger) ---
      switch (p) {
        case 0: stage(4 * (2 * ii + 1) + 3); break;                         // B1(2i+1)
        case 1: stage(4 * (2 * ii + 1) + 0); stage(4 * (2 * ii + 1) + 1); break; // A(2i+1)
        case 3: stage(4 * (2 * ii + 2) + 2); break;                         // B0(2i+2)
        case 4: stage(4 * (2 * ii + 2) + 3); break;                         // B1(2i+2)
        case 5: stage(4 * (2 * ii + 2) + 0); stage(4 * (2 * ii + 2) + 1); break; // A(2i+2)
        case 7: stage(4 * (2 * ii + 3) + 2); break;                         // B0(2i+3)
      }
      if (p == 3 || p == 7) {
        if (ii == NITER - 1) asm volatile("s_waitcnt vmcnt(0)" ::: "memory");
        else                 asm volatile("s_waitcnt vmcnt(2)" ::: "memory");
      }
      __builtin_amdgcn_s_barrier();
      // --- post-barrier prefetch of NEXT phase's aq (same tile-half only) ---
      if (q < 3) {
        #pragma unroll
        for (int i = 0; i < 2; ++i) {
          const int R = wm * 128 + ((q + 1) * 2 + i) * 16 + lr;
          #pragma unroll
          for (int kk = 0; kk < 2; ++kk)
            aqbuf[(p + 1) & 1][i][kk] = *(const bf16x8*)(Ab + R * 128 + ((kk * 64 + lg * 16) ^ koff));
        }
        asm volatile("s_waitcnt lgkmcnt(4)" ::: "memory");  // drain cur, keep prefetch
      } else {
        asm volatile("s_waitcnt lgkmcnt(0)" ::: "memory");
      }
      // --- MFMA cluster: one C-quadrant (2 m-frags x 4 n-frags) x K=64 ---
      __builtin_amdgcn_s_setprio(1);
      #pragma unroll
      for (int i = 0; i < 2; ++i)
        #pragma unroll
        for (int nj = 0; nj < 4; ++nj)
          #pragma unroll
          for (int kk = 0; kk < 2; ++kk)
            acc[q * 2 + i][nj] = __builtin_amdgcn_mfma_f32_16x16x32_bf16(
                aqbuf[p & 1][i][kk], bq[nj][kk], acc[q * 2 + i][nj], 0, 0, 0);
      __builtin_amdgcn_s_setprio(0);
      // (no post-MFMA barrier)
    }
  }

  // epilogue: C = acc + bias ; C/D layout col=lane&15, row=(lane>>4)*4+reg
  #pragma unroll
  for (int nj = 0; nj < 4; ++nj) {
    const int col = bn * 256 + wn * 64 + nj * 16 + lr;
    const float bv = bias[col];
    #pragma unroll
    for (int mi = 0; mi < 8; ++mi) {
      const int row0 = bm * 256 + wm * 128 + mi * 16 + lg * 4;
      #pragma unroll
      for (int rr = 0; rr < 4; ++rr)
        C[(size_t)(row0 + rr) * OUT_ + col] = acc[mi][nj][rr] + bv;
    }
  }
}

extern "C" void kernel_launch(void* const* d_in, const int* in_sizes, int n_in,
                              void* d_out, int out_size, void* d_ws, size_t ws_size,
                              hipStream_t stream) {
  const float* x  = (const float*)d_in[0];   // [4,4096,2048]
  const float* Wb = (const float*)d_in[1];   // [2048,2048]
  const float* bb = (const float*)d_in[2];   // [2048]
  const float* rW = (const float*)d_in[3];   // [8,2048]
  const float* A  = (const float*)d_in[4];   // [8,16,2048]
  const float* Bw = (const float*)d_in[5];   // [8,2048,16]
  float* out = (float*)d_out;                // [4,4096,2048] fp32

  ushort_t* xext = (ushort_t*)d_ws;                                   // M_ x KX bf16
  ushort_t* wext = (ushort_t*)((char*)d_ws + (size_t)M_ * KX * 2);    // OUT_ x KX bf16
  ushort_t* aext = (ushort_t*)((char*)d_ws + (size_t)M_ * KX * 2
                                           + (size_t)OUT_ * KX * 2);  // 128 x D_ bf16

  wprep_all_kernel<<<OUT_ + (E_ * R_ * D_) / (256 * 8), 256, 0, stream>>>(Wb, Bw, A, wext, aext);
  hrouter_kernel<<<M_ / 32, 256, 0, stream>>>(x, rW, aext, xext);
  gemm_kernel<<<(M_ / 256) * (OUT_ / 256), 512, 0, stream>>>(xext, wext, bb, out);
}

// Round 21
// 235.266 us; speedup vs baseline: 1.0909x; 1.0909x over previous
//
#include <hip/hip_runtime.h>

// Problem constants
#define D_    2048
#define OUT_  2048
#define E_    8
#define R_    16
#define KX    2176          // D_ + E_*R_  (K-extended GEMM depth)
#define M_    16384         // B*S tokens
#define SCALING_F 2.0f      // ALPHA / R = 32/16

typedef unsigned short ushort_t;
typedef unsigned short ushort8 __attribute__((ext_vector_type(8)));
typedef __bf16 bf16x8 __attribute__((ext_vector_type(8)));
typedef float f32x4 __attribute__((ext_vector_type(4)));

__device__ __forceinline__ ushort_t f2bf(float f) {
  unsigned u = __float_as_uint(f);
  u += 0x7FFFu + ((u >> 16) & 1u);   // round-to-nearest-even
  return (ushort_t)(u >> 16);
}

#define GLOAD16(gp, lp)                                                        \
  __builtin_amdgcn_global_load_lds(                                            \
      (const __attribute__((address_space(1))) void*)(gp),                     \
      (__attribute__((address_space(3))) void*)(lp), 16, 0, 0)

// -------- W_ext + A_ext prep (fused): wext[OUT_][KX], aext[128][D_] bf16 ----
__global__ __launch_bounds__(256) void wprep_all_kernel(
    const float* __restrict__ W, const float* __restrict__ Bw,
    const float* __restrict__ A,
    ushort_t* __restrict__ wext, ushort_t* __restrict__ aext)
{
  const int bid = blockIdx.x;
  const int t = threadIdx.x;
  if (bid < OUT_) {
    const int o = bid;
    const float* wr = W + (size_t)o * D_ + t * 8;
    float4 v0 = *(const float4*)wr;
    float4 v1 = *(const float4*)(wr + 4);
    ushort8 wb;
    wb[0] = f2bf(v0.x); wb[1] = f2bf(v0.y); wb[2] = f2bf(v0.z); wb[3] = f2bf(v0.w);
    wb[4] = f2bf(v1.x); wb[5] = f2bf(v1.y); wb[6] = f2bf(v1.z); wb[7] = f2bf(v1.w);
    *(ushort8*)(wext + (size_t)o * KX + t * 8) = wb;
    if (t < E_ * R_) {
      const int e = t >> 4, r = t & 15;
      wext[(size_t)o * KX + D_ + t] = f2bf(Bw[((size_t)e * OUT_ + o) * R_ + r]);
    }
  } else {
    const size_t i = ((size_t)(bid - OUT_) * 256 + t) * 8;
    float4 v0 = *(const float4*)(A + i);
    float4 v1 = *(const float4*)(A + i + 4);
    ushort8 b;
    b[0] = f2bf(v0.x); b[1] = f2bf(v0.y); b[2] = f2bf(v0.z); b[3] = f2bf(v0.w);
    b[4] = f2bf(v1.x); b[5] = f2bf(v1.y); b[6] = f2bf(v1.z); b[7] = f2bf(v1.w);
    *(ushort8*)(aext + i) = b;
  }
}

// ---- FUSED h GEMM + router + x convert (r10/r16/r19 best-measured) ---------
#define HG_NKT (D_ / 64)     // 32 K-tiles

__global__ __launch_bounds__(256) void hrouter_kernel(
    const float* __restrict__ x,       // [M_][D_] fp32
    const float* __restrict__ rW,      // [E_][D_] fp32
    const ushort_t* __restrict__ Ae,   // [128][D_] bf16
    ushort_t* __restrict__ xext)       // writes all KX cols
{
  __shared__ __attribute__((aligned(16))) char lds[40960];  // 2 x (4KB X + 16KB A)
  __shared__ int esel[32];

  const int t = threadIdx.x;
  const int lane = t & 63, w = t >> 6;
  const int wr = w >> 1, wc = w & 1;          // wave tile 16 rows x 64 cols
  const int lr = lane & 15, lg = lane >> 4;
  const int koff = (lr & 7) << 4;

  const int bm = blockIdx.x;                   // 512 blocks x 32 rows
  const size_t row0 = (size_t)bm * 32;

  const int sg_row = t >> 3;                   // 0..31
  const int sg_c = t & 7;                      // col chunk (8 bf16)
  const int sg_slotx = sg_c ^ (sg_row & 7);    // pre-swizzled slot

  auto stageA = [&](int TT) {
    char* dst = lds + (TT & 1) * 20480 + 4096;
    #pragma unroll
    for (int g = 0; g < 4; ++g) {
      const int r = g * 32 + sg_row;
      GLOAD16(Ae + (size_t)r * D_ + TT * 64 + sg_slotx * 8,
              dst + g * 4096 + t * 16);
    }
  };
  auto putX = [&](int TT, const float4& a, const float4& b) {
    ushort8 xb;
    xb[0] = f2bf(a.x); xb[1] = f2bf(a.y); xb[2] = f2bf(a.z); xb[3] = f2bf(a.w);
    xb[4] = f2bf(b.x); xb[5] = f2bf(b.y); xb[6] = f2bf(b.z); xb[7] = f2bf(b.w);
    char* Xb = lds + (TT & 1) * 20480;
    *(ushort8*)(Xb + sg_row * 128 + sg_slotx * 16) = xb;
    *(ushort8*)(xext + (row0 + sg_row) * KX + TT * 64 + sg_c * 8) = xb;
  };

  float la[E_];
  #pragma unroll
  for (int e = 0; e < E_; ++e) la[e] = 0.f;
  // accumulate this thread's 8-element slice of the row's router logits
  auto accLogit = [&](int TT, const float4& a, const float4& b) {
    const float* wp = rW + TT * 64 + sg_c * 8;
    #pragma unroll
    for (int e = 0; e < E_; ++e) {
      float4 w0 = *(const float4*)(wp + (size_t)e * D_);
      float4 w1 = *(const float4*)(wp + (size_t)e * D_ + 4);
      la[e] += a.x * w0.x + a.y * w0.y + a.z * w0.z + a.w * w0.w
             + b.x * w1.x + b.y * w1.y + b.z * w1.z + b.w * w1.w;
    }
  };

  f32x4 acc[4] = {};

  {
    const float* xp = x + (row0 + sg_row) * D_ + sg_c * 8;
    float4 a = *(const float4*)xp;
    float4 b = *(const float4*)(xp + 4);
    stageA(0);
    putX(0, a, b);
    accLogit(0, a, b);
  }
  __syncthreads();

  for (int T = 0; T < HG_NKT; ++T) {
    float4 na, nb;
    const bool more = (T + 1 < HG_NKT);
    if (more) {
      const float* xp = x + (row0 + sg_row) * D_ + (T + 1) * 64 + sg_c * 8;
      na = *(const float4*)xp;
      nb = *(const float4*)(xp + 4);
      stageA(T + 1);
    }
    char* Xb = lds + (T & 1) * 20480;
    char* Ab = Xb + 4096;
    bf16x8 af[2], bfr[4][2];
    #pragma unroll
    for (int kk = 0; kk < 2; ++kk)
      af[kk] = *(const bf16x8*)(Xb + (wr * 16 + lr) * 128 + ((kk * 64 + lg * 16) ^ koff));
    #pragma unroll
    for (int nj = 0; nj < 4; ++nj) {
      const int R = wc * 64 + nj * 16 + lr;
      #pragma unroll
      for (int kk = 0; kk < 2; ++kk)
        bfr[nj][kk] = *(const bf16x8*)(Ab + R * 128 + ((kk * 64 + lg * 16) ^ koff));
    }
    #pragma unroll
    for (int nj = 0; nj < 4; ++nj)
      #pragma unroll
      for (int kk = 0; kk < 2; ++kk)
        acc[nj] = __builtin_amdgcn_mfma_f32_16x16x32_bf16(af[kk], bfr[nj][kk], acc[nj], 0, 0, 0);
    if (more) {
      putX(T + 1, na, nb);
      accLogit(T + 1, na, nb);
    }
    __syncthreads();   // full drain: vmcnt (Ae tile) + lgkm (Xb writes)
  }

  // router finish: 8-lane group (one x-row) fp64 tree reduce + first-max argmax
  {
    double s[E_];
    #pragma unroll
    for (int e = 0; e < E_; ++e) s[e] = (double)la[e];
    #pragma unroll
    for (int off = 1; off <= 4; off <<= 1)
      #pragma unroll
      for (int e = 0; e < E_; ++e) s[e] += __shfl_xor(s[e], off, 64);
    int bi = 0; double best = s[0];
    #pragma unroll
    for (int e = 1; e < E_; ++e)
      if (s[e] > best) { best = s[e]; bi = e; }   // first-max tie-break
    if (sg_c == 0) esel[sg_row] = bi;
  }
  __syncthreads();

  // masked epilogue: xext[row][D_+col] = (esel[row]==col>>4) ? bf16(2*h) : 0
  int er[4];
  #pragma unroll
  for (int rr = 0; rr < 4; ++rr)
    er[rr] = esel[wr * 16 + lg * 4 + rr];
  #pragma unroll
  for (int nj = 0; nj < 4; ++nj) {
    const int col = wc * 64 + nj * 16 + lr;
    const int ecol = wc * 4 + nj;              // col>>4, wave-uniform per nj
    #pragma unroll
    for (int rr = 0; rr < 4; ++rr) {
      const size_t row = row0 + wr * 16 + lg * 4 + rr;
      ushort_t v = (er[rr] == ecol) ? f2bf(acc[nj][rr] * SCALING_F) : (ushort_t)0;
      xext[row * KX + D_ + col] = v;
    }
  }
}

// ------------- GEMM: 256x256, 8-phase, ONE barrier per phase ----------------
// r17 best-measured configuration (gemm 135.7 us, MfmaUtil 47%), byte-exact.
// Lever ledger (this session): barrier density 272/136/68 = 144.7/135.7/139.4
// -> 136 optimum; stage-order variants null; memory locality null (r15:
// 2.65x FETCH -> +-3%); epilogue swap null; register prefetch -29 us
// regression (r20: source-level scheduling defeats compiler, m141-class).
// Ledger (proven race-free, see r17):
//   p0: B1(2i+1)->buf1.B ; p1: A0+A1(2i+1)->buf1.A ; p3: B0(2i+2)->buf0.B
//       + vmcnt(2) pre-barrier (drains tile 2i+1 for p4; last iter vmcnt(0))
//   p4: B1(2i+2)->buf0.B ; p5: A0+A1(2i+2)->buf0.A ; p7: B0(2i+3)->buf1.B
//       + vmcnt(2) pre-barrier (drains tile 2i+2 for next p0)
// Stage targets never intersect reads(p-1) U reads(p); laggard reads drain
// via their lgkm0 which precedes the next barrier in program order.
#define NKT (KX / 64)        // 34 K-tiles
#define NITER (NKT / 2)      // 17 iterations
#define NSTG (NKT * 4)       // 136 half-tile stages

__global__ __launch_bounds__(512, 2) void gemm_kernel(
    const ushort_t* __restrict__ Ag,   // [M_][KX] bf16
    const ushort_t* __restrict__ Bg,   // [OUT_][KX] bf16
    const float* __restrict__ bias,
    float* __restrict__ C)
{
  __shared__ __attribute__((aligned(16))) char lds[131072];

  const int t = threadIdx.x;
  const int lane = t & 63, w = t >> 6;
  const int wm = w >> 2, wn = w & 3;          // 2x4 wave grid; wave tile 128x64
  const int lr = lane & 15, lg = lane >> 4;
  const int koff = (lr & 7) << 4;             // read-side swizzle XOR (bytes)

  // XCD-bijective blockIdx swizzle (512 % 8 == 0)
  const int swz = (blockIdx.x & 7) * 64 + (blockIdx.x >> 3);
  const int bm = swz >> 3, bn = swz & 7;

  const int sg_row = t >> 3;
  const int sg_slotx = (t & 7) ^ ((t >> 3) & 7);   // pre-swizzled source slot
  const size_t aRow0 = (size_t)bm * 256;
  const size_t bRow0 = (size_t)bn * 256;

  // stage half-tile s: tile TT=s>>2, j=s&3 (0,1 = A halves; 2,3 = B halves)
  auto stage = [&](int s) {
    if (s >= NSTG) return;
    const int TT = s >> 2, j = s & 3;
    const int isB = j >> 1, half = j & 1;
    const ushort_t* src = isB ? Bg : Ag;
    const size_t gr0 = (isB ? bRow0 : aRow0) + half * 128;
    char* dst = lds + (TT & 1) * 65536 + isB * 32768 + half * 16384;
    #pragma unroll
    for (int g = 0; g < 2; ++g) {
      const int r = g * 64 + sg_row;
      GLOAD16(src + (gr0 + r) * KX + TT * 64 + sg_slotx * 8,
              dst + g * 8192 + t * 16);
    }
  };

  f32x4 acc[8][4] = {};
  bf16x8 bq[4][2];

  // prologue: tile0 {A0,A1,B0,B1} + B0(1); wait tile0 landed, B0(1) in flight.
  stage(0); stage(1); stage(2); stage(3);
  stage(6);
  asm volatile("s_waitcnt vmcnt(2)" ::: "memory");
  __builtin_amdgcn_s_barrier();

  for (int ii = 0; ii < NITER; ++ii) {
    #pragma unroll
    for (int p = 0; p < 8; ++p) {
      const int q = p & 3;
      char* Ab = lds + ((2 * ii + (p >> 2)) & 1) * 65536;
      char* Bb = Ab + 32768;
      // --- ds-load register subtile ---
      bf16x8 aq[2][2];
      if (q == 0) {
        #pragma unroll
        for (int nj = 0; nj < 4; ++nj) {
          const int R = wn * 64 + nj * 16 + lr;
          #pragma unroll
          for (int kk = 0; kk < 2; ++kk)
            bq[nj][kk] = *(const bf16x8*)(Bb + R * 128 + ((kk * 64 + lg * 16) ^ koff));
        }
      }
      #pragma unroll
      for (int i = 0; i < 2; ++i) {
        const int R = wm * 128 + (q * 2 + i) * 16 + lr;
        #pragma unroll
        for (int kk = 0; kk < 2; ++kk)
          aq[i][kk] = *(const bf16x8*)(Ab + R * 128 + ((kk * 64 + lg * 16) ^ koff));
      }
      // --- 1-barrier stage map (ledger in header comment) ---
      switch (p) {
        case 0: stage(4 * (2 * ii + 1) + 3); break;                         // B1(2i+1)
        case 1: stage(4 * (2 * ii + 1) + 0); stage(4 * (2 * ii + 1) + 1); break; // A(2i+1)
        case 3: stage(4 * (2 * ii + 2) + 2); break;                         // B0(2i+2)
        case 4: stage(4 * (2 * ii + 2) + 3); break;                         // B1(2i+2)
        case 5: stage(4 * (2 * ii + 2) + 0); stage(4 * (2 * ii + 2) + 1); break; // A(2i+2)
        case 7: stage(4 * (2 * ii + 3) + 2); break;                         // B0(2i+3)
      }
      // --- counted drains BEFORE the barrier of the phase preceding the
      //     first read of freshly staged data ---
      if (p == 3) {
        if (ii == NITER - 1) asm volatile("s_waitcnt vmcnt(0)" ::: "memory");
        else                 asm volatile("s_waitcnt vmcnt(2)" ::: "memory");
      } else if (p == 7) {
        if (ii == NITER - 1) asm volatile("s_waitcnt vmcnt(0)" ::: "memory");
        else                 asm volatile("s_waitcnt vmcnt(2)" ::: "memory");
      }
      __builtin_amdgcn_s_barrier();
      asm volatile("s_waitcnt lgkmcnt(0)" ::: "memory");
      // --- MFMA cluster: one C-quadrant (2 m-frags x 4 n-frags) x K=64 ---
      __builtin_amdgcn_s_setprio(1);
      #pragma unroll
      for (int i = 0; i < 2; ++i)
        #pragma unroll
        for (int nj = 0; nj < 4; ++nj)
          #pragma unroll
          for (int kk = 0; kk < 2; ++kk)
            acc[q * 2 + i][nj] = __builtin_amdgcn_mfma_f32_16x16x32_bf16(
                aq[i][kk], bq[nj][kk], acc[q * 2 + i][nj], 0, 0, 0);
      __builtin_amdgcn_s_setprio(0);
      // (no post-MFMA barrier)
    }
  }

  // epilogue: C = acc + bias ; C/D layout col=lane&15, row=(lane>>4)*4+reg
  #pragma unroll
  for (int nj = 0; nj < 4; ++nj) {
    const int col = bn * 256 + wn * 64 + nj * 16 + lr;
    const float bv = bias[col];
    #pragma unroll
    for (int mi = 0; mi < 8; ++mi) {
      const int row0 = bm * 256 + wm * 128 + mi * 16 + lg * 4;
      #pragma unroll
      for (int rr = 0; rr < 4; ++rr)
        C[(size_t)(row0 + rr) * OUT_ + col] = acc[mi][nj][rr] + bv;
    }
  }
}

extern "C" void kernel_launch(void* const* d_in, const int* in_sizes, int n_in,
                              void* d_out, int out_size, void* d_ws, size_t ws_size,
                              hipStream_t stream) {
  const float* x  = (const float*)d_in[0];   // [4,4096,2048]
  const float* Wb = (const float*)d_in[1];   // [2048,2048]
  const float* bb = (const float*)d_in[2];   // [2048]
  const float* rW = (const float*)d_in[3];   // [8,2048]
  const float* A  = (const float*)d_in[4];   // [8,16,2048]
  const float* Bw = (const float*)d_in[5];   // [8,2048,16]
  float* out = (float*)d_out;                // [4,4096,2048] fp32

  ushort_t* xext = (ushort_t*)d_ws;                                   // M_ x KX bf16
  ushort_t* wext = (ushort_t*)((char*)d_ws + (size_t)M_ * KX * 2);    // OUT_ x KX bf16
  ushort_t* aext = (ushort_t*)((char*)d_ws + (size_t)M_ * KX * 2
                                           + (size_t)OUT_ * KX * 2);  // 128 x D_ bf16

  wprep_all_kernel<<<OUT_ + (E_ * R_ * D_) / (256 * 8), 256, 0, stream>>>(Wb, Bw, A, wext, aext);
  hrouter_kernel<<<M_ / 32, 256, 0, stream>>>(x, rW, aext, xext);
  gemm_kernel<<<(M_ / 256) * (OUT_ / 256), 512, 0, stream>>>(xext, wext, bb, out);
}